// Round 5
// baseline (17.655 us; speedup 1.0000x reference)
//
#include <hip/hip_runtime.h>
#include <math.h>

// Problem constants: B=1024, IN_DIM=4096, OUT_DIM=4096, FAN_IN=8
#define BDIM 1024
#define IN_DIM 4096
#define OUT_DIM 4096
#define FAN_IN 8
#define NT 512
#define TILE_B 2
#define OPT (OUT_DIM / NT)   // 8 outputs per thread

#define LOG2E 1.442695040888963f

__device__ __forceinline__ float fast_exp(float v) {
    return exp2f(v * LOG2E);   // v_exp_f32
}

__global__ __launch_bounds__(NT, 4) void WeightedThresholdGate_53085795778563_kernel(
    const float* __restrict__ x,      // [B, IN_DIM]
    const int*   __restrict__ idx,    // [OUT_DIM, FAN_IN]
    const float* __restrict__ w,      // [OUT_DIM, FAN_IN]
    const float* __restrict__ theta,  // [OUT_DIM]
    const float* __restrict__ s_raw,  // [OUT_DIM]
    float*       __restrict__ out)    // [B, OUT_DIM]
{
    // Transposed pair-stage: xT2[j] = {x[b0][j], x[b0+1][j]}; one ds_read_b64
    // at index j yields the gathered value for both batch rows. 32 KiB ->
    // 2 blocks/CU co-resident: one block's stage overlaps the other's gather.
    __shared__ __align__(16) float xT[IN_DIM * TILE_B];

    const int t  = threadIdx.x;
    const int b0 = blockIdx.x * TILE_B;

    const float2* __restrict__ xr0 =
        reinterpret_cast<const float2*>(x + (size_t)(b0 + 0) * IN_DIM);
    const float2* __restrict__ xr1 =
        reinterpret_cast<const float2*>(x + (size_t)(b0 + 1) * IN_DIM);

    // Staging: thread t, iter k handles j-pair jp -> dwordx2 loads per row
    // (each wave reads 512B contiguous: coalesced), interleave in registers,
    // single lane-contiguous ds_write_b128 (conflict-free).
#pragma unroll
    for (int k = 0; k < IN_DIM / (2 * NT); ++k) {
        const int jp = t + k * NT;           // pair index: j = 2*jp
        const float2 a0 = xr0[jp];
        const float2 a1 = xr1[jp];
        float4 v;
        v.x = a0.x; v.y = a1.x;              // xT2[2*jp]
        v.z = a0.y; v.w = a1.y;              // xT2[2*jp+1]
        reinterpret_cast<float4*>(xT)[jp] = v;
    }
    __syncthreads();

    const float2* __restrict__ xT2 = reinterpret_cast<const float2*>(xT);

#pragma unroll 2
    for (int i = 0; i < OPT; ++i) {
        const int o = t + i * NT;

        const int4*   ip = reinterpret_cast<const int4*>(idx + (size_t)o * FAN_IN);
        const float4* wp = reinterpret_cast<const float4*>(w  + (size_t)o * FAN_IN);
        const int4   i0 = ip[0], i1 = ip[1];
        const float4 w0 = wp[0], w1 = wp[1];

        float accx = 0.f, accy = 0.f;
        float2 v;

        v = xT2[i0.x]; accx = fmaf(v.x, w0.x, accx); accy = fmaf(v.y, w0.x, accy);
        v = xT2[i0.y]; accx = fmaf(v.x, w0.y, accx); accy = fmaf(v.y, w0.y, accy);
        v = xT2[i0.z]; accx = fmaf(v.x, w0.z, accx); accy = fmaf(v.y, w0.z, accy);
        v = xT2[i0.w]; accx = fmaf(v.x, w0.w, accx); accy = fmaf(v.y, w0.w, accy);
        v = xT2[i1.x]; accx = fmaf(v.x, w1.x, accx); accy = fmaf(v.y, w1.x, accy);
        v = xT2[i1.y]; accx = fmaf(v.x, w1.y, accx); accy = fmaf(v.y, w1.y, accy);
        v = xT2[i1.z]; accx = fmaf(v.x, w1.z, accx); accy = fmaf(v.y, w1.z, accy);
        v = xT2[i1.w]; accx = fmaf(v.x, w1.w, accx); accy = fmaf(v.y, w1.w, accy);

        const float th = theta[o];
        const float sr = s_raw[o];
        // softplus(sr) + 1e-6, stable: max(sr,0) + log1p(exp(-|sr|))
        const float sp = fmaxf(sr, 0.0f) + log1pf(fast_exp(-fabsf(sr)));
        const float s  = sp + 1e-6f;

        const float g0 = 1.0f / (1.0f + fast_exp(-s * (accx - th)));
        const float g1 = 1.0f / (1.0f + fast_exp(-s * (accy - th)));

        // Streamed output: nontemporal, keep L2 for idx/w broadcast + x reuse
        __builtin_nontemporal_store(g0, &out[(size_t)(b0 + 0) * OUT_DIM + o]);
        __builtin_nontemporal_store(g1, &out[(size_t)(b0 + 1) * OUT_DIM + o]);
    }
}

extern "C" void kernel_launch(void* const* d_in, const int* in_sizes, int n_in,
                              void* d_out, int out_size, void* d_ws, size_t ws_size,
                              hipStream_t stream) {
    const float* x     = (const float*)d_in[0];
    const int*   idx   = (const int*)  d_in[1];
    const float* w     = (const float*)d_in[2];
    const float* theta = (const float*)d_in[3];
    const float* s_raw = (const float*)d_in[4];
    float* out = (float*)d_out;

    dim3 grid(BDIM / TILE_B);   // 512 blocks -> 2 blocks/CU co-resident
    dim3 block(NT);             // 512 threads = 8 waves (4 waves/SIMD total)
    WeightedThresholdGate_53085795778563_kernel<<<grid, block, 0, stream>>>(
        x, idx, w, theta, s_raw, out);
}